// Round 15
// baseline (62.875 us; speedup 1.0000x reference)
//
#include <hip/hip_runtime.h>

typedef float v2f __attribute__((ext_vector_type(2)));

// Canonical wave64 inclusive prefix-sum (AMD GCN scan sequence).
__device__ __forceinline__ float scan64(float d) {
    d += __int_as_float(__builtin_amdgcn_update_dpp(0, __float_as_int(d), 0x111, 0xF, 0xF, true));
    d += __int_as_float(__builtin_amdgcn_update_dpp(0, __float_as_int(d), 0x112, 0xF, 0xF, true));
    d += __int_as_float(__builtin_amdgcn_update_dpp(0, __float_as_int(d), 0x114, 0xF, 0xF, true));
    d += __int_as_float(__builtin_amdgcn_update_dpp(0, __float_as_int(d), 0x118, 0xF, 0xF, true));
    d += __int_as_float(__builtin_amdgcn_update_dpp(0, __float_as_int(d), 0x142, 0xA, 0xF, true));
    d += __int_as_float(__builtin_amdgcn_update_dpp(0, __float_as_int(d), 0x143, 0xC, 0xF, true));
    return d;
}

// wave-uniform broadcast of lane 63 (no LDS round-trip)
__device__ __forceinline__ float rdl63(float v) {
    return __int_as_float(__builtin_amdgcn_readlane(__float_as_int(v), 63));
}

// Software-pipelined waveform kernel: iteration g runs sweep1(block g) and
// linearized sweep2(block g-1) as INDEPENDENT chains in one basic block, so
// the scheduler interleaves sweep2's full-rate VALU into sweep1's trans/scan
// latency. The block-(g+1) predictor uses the sweep1-only carry
// (y0ap = Y + rdl63(S1tot), err ~1e-4); sweep2's linearization absorbs the
// predictor error via dz, and outputs stay anchored to the exact carry Y.
__global__ __launch_bounds__(64, 4) void ode_wf64pipe(
    const float* __restrict__ thr,   // B x (N+1)
    const float* __restrict__ DOD,   // B
    const float* __restrict__ Vav,   // B
    const float* __restrict__ C0,    // B
    const float* __restrict__ R0,    // B
    const float* __restrict__ W1,    // 10 x 5
    const float* __restrict__ b1,    // 10
    const float* __restrict__ W2,    // 5 x 10
    const float* __restrict__ b2,    // 5
    float* __restrict__ out,         // B x (N+1) x 2
    int B, int N)
{
    const int j   = threadIdx.x & 63;   // step-slot within a 64-step block
    const int row = blockIdx.x;         // 1 row per wave
    if (row >= B) return;

    // tanh(p) = 1 - 2/(1+e^{2p}); fold 2*log2(e) into layer-1, "+1" into
    // c3/c4, "-2" into wa/wb. Hidden units packed (h, h+5) -> v_pk_* fp32.
    const float k2  = 2.0f * 1.4426950408889634f;
    const float ln2 = 0.6931471805599453f;
    const float dod = DOD[row], vav = Vav[row];

    v2f bw[5], w0k[5], w3k[5], w4k[5], wa[5], wb[5];
    float c3 = b2[3], c4 = b2[4];
#pragma unroll
    for (int i = 0; i < 5; ++i) {
#pragma unroll
        for (int p = 0; p < 2; ++p) {
            int h = i + 5 * p;
            float a0 = W1[h * 5 + 0];
            float a1 = W1[h * 5 + 1];
            float a2 = W1[h * 5 + 2];
            float a3 = W1[h * 5 + 3];
            float a4 = W1[h * 5 + 4];
            bw[i][p]  = k2 * (b1[h] + a1 * dod + a2 * vav);
            w0k[i][p] = k2 * a0;
            w3k[i][p] = k2 * a3;
            w4k[i][p] = k2 * a4;
            float v3 = W2[30 + h];
            float v4 = W2[40 + h];
            c3 += v3; c4 += v4;
            wa[i][p] = -2.0f * v3;
            wb[i][p] = -2.0f * v4;
        }
    }

    float Y3 = C0[row], Y4 = R0[row];   // EXACT state at start of oldest block
    const float* trp = thr + (size_t)row * (size_t)(N + 1);
    float2* orow = (float2*)(out + (size_t)row * (size_t)(N + 1) * 2);
    if (j == 0) orow[0] = make_float2(Y3, Y4);

    // sweep1: full MLP eval at z, scan of h*F (keeps s for the Jacobian)
    auto SWEEP1 = [&](float z3_, float z4_, float tj_, float hj_, v2f* sv_,
                      float& F3_, float& F4_, float& d3_, float& d4_,
                      float& S3_, float& S4_) {
        v2f Fa = {c3, 0.f}, Fb = {c4, 0.f};
#pragma unroll
        for (int i = 0; i < 5; ++i) {
            v2f x = w3k[i] * z3_ + (w4k[i] * z4_ + (w0k[i] * tj_ + bw[i]));
            v2f e; e.x = __builtin_amdgcn_exp2f(x.x);
                   e.y = __builtin_amdgcn_exp2f(x.y);
            v2f A = e + 1.0f;
            v2f s; s.x = __builtin_amdgcn_rcpf(A.x);
                   s.y = __builtin_amdgcn_rcpf(A.y);
            sv_[i] = s;
            Fa += wa[i] * s;
            Fb += wb[i] * s;
        }
        F3_ = Fa.x + Fa.y; F4_ = Fb.x + Fb.y;
        d3_ = hj_ * F3_;   d4_ = hj_ * F4_;
        S3_ = scan64(d3_); S4_ = scan64(d4_);
    };
    // sweep2: linearized correction (zero trans), final scan
    auto SWEEP2 = [&](const v2f* sv_, float F3_, float F4_, float d3_, float d4_,
                      float S3_, float S4_, float hj_, float z3_, float z4_,
                      float& S23_, float& S24_) {
        float dz3 = (Y3 + (S3_ - d3_)) - z3_;
        float dz4 = (Y4 + (S4_ - d4_)) - z4_;
        v2f a3 = {0.f, 0.f}, a4 = {0.f, 0.f};
#pragma unroll
        for (int i = 0; i < 5; ++i) {
            v2f dx = w3k[i] * dz3 + w4k[i] * dz4;
            v2f s  = sv_[i];
            v2f t  = s - s * s;              // s*(1-s)
            v2f u  = dx * t;
            a3 += wa[i] * u;
            a4 += wb[i] * u;
        }
        float F23 = fmaf(-ln2, a3.x + a3.y, F3_);
        float F24 = fmaf(-ln2, a4.x + a4.y, F4_);
        float d23 = hj_ * F23, d24 = hj_ * F24;
        S23_ = scan64(d23);
        S24_ = scan64(d24);
    };

    // t for block 0 + prefetch block 1
    float tj  = trp[min(j, N)];
    float tj1 = trp[min(j + 1, N)];
    float t0  = trp[0];
    float ptj  = trp[min(64 + j, N)];
    float ptj1 = trp[min(64 + j + 1, N)];
    float pt0  = trp[min(64, N)];

    // bootstrap slope F(Y, t0)
    float F3p, F4p;
    {
        v2f Fa = {c3, 0.f}, Fb = {c4, 0.f};
#pragma unroll
        for (int i = 0; i < 5; ++i) {
            v2f x = w3k[i] * Y3 + (w4k[i] * Y4 + (w0k[i] * t0 + bw[i]));
            v2f e; e.x = __builtin_amdgcn_exp2f(x.x); e.y = __builtin_amdgcn_exp2f(x.y);
            v2f A = e + 1.0f;
            v2f s; s.x = __builtin_amdgcn_rcpf(A.x); s.y = __builtin_amdgcn_rcpf(A.y);
            Fa += wa[i] * s;
            Fb += wb[i] * s;
        }
        F3p = Fa.x + Fa.y; F4p = Fb.x + Fb.y;
    }

    // predictor for block 0 (1st order: dF unknown yet)
    float z3 = fmaf(tj - t0, F3p, Y3);
    float z4 = fmaf(tj - t0, F4p, Y4);

    const int nblk = (N + 63) >> 6;

    // ---- peel: sweep1(block 0) ----
    v2f  svP[5];
    float F13P, F14P, d13P, d14P, S13P, S14P, hjP, z3P, z4P;
    hjP = tj1 - tj;
    SWEEP1(z3, z4, tj, hjP, svP, F13P, F14P, d13P, d14P, S13P, S14P);
    z3P = z3; z4P = z4;
    // predictor for block 1 from sweep1-only carry
    {
        float F3n = rdl63(F13P), F4n = rdl63(F14P);
        float y0ap3 = Y3 + rdl63(S13P), y0ap4 = Y4 + rdl63(S14P);
        float span = pt0 - t0;
        float inv = (span > 0.f) ? __builtin_amdgcn_rcpf(span) : 0.f;
        float dFn3 = (F3n - F3p) * inv, dFn4 = (F4n - F4p) * inv;
        float dtn = ptj - pt0;
        z3 = fmaf(dtn, fmaf(0.5f * dtn, dFn3, F3n), y0ap3);
        z4 = fmaf(dtn, fmaf(0.5f * dtn, dFn4, F4n), y0ap4);
        F3p = F3n; F4p = F4n;
    }
    tj = ptj; tj1 = ptj1; t0 = pt0;

    // ---- main loop: sweep1(g) || sweep2(g-1) ----
    for (int g = 1; g < nblk; ++g) {
        const int nb = (g + 1) << 6;
        // prefetch block g+1 (always clamped: keeps one basic block)
        ptj  = trp[min(nb + j, N)];
        ptj1 = trp[min(nb + j + 1, N)];
        pt0  = trp[min(nb, N)];

        // sweep1 for block g (independent of sweep2 below -> interleaves)
        v2f sv[5];
        float F13, F14, d13, d14, S13, S14;
        float hj = tj1 - tj;
        SWEEP1(z3, z4, tj, hj, sv, F13, F14, d13, d14, S13, S14);

        // sweep2 for block g-1 (uses *_P regs + exact Y)
        float S23, S24;
        SWEEP2(svP, F13P, F14P, d13P, d14P, S13P, S14P, hjP, z3P, z4P, S23, S24);
        const int pbase = (g - 1) << 6;
        if (pbase + j < N)
            orow[pbase + j + 1] = make_float2(Y3 + S23, Y4 + S24);
        Y3 += rdl63(S23);                    // exact start of block g
        Y4 += rdl63(S24);

        // predictor for block g+1 from sweep1-only carry
        float F3n = rdl63(F13), F4n = rdl63(F14);
        float y0ap3 = Y3 + rdl63(S13), y0ap4 = Y4 + rdl63(S14);
        float span = pt0 - t0;
        float inv = (span > 0.f) ? __builtin_amdgcn_rcpf(span) : 0.f;
        float dFn3 = (F3n - F3p) * inv, dFn4 = (F4n - F4p) * inv;
        float dtn = ptj - pt0;
        float z3n = fmaf(dtn, fmaf(0.5f * dtn, dFn3, F3n), y0ap3);
        float z4n = fmaf(dtn, fmaf(0.5f * dtn, dFn4, F4n), y0ap4);

        // rotate pipeline registers
#pragma unroll
        for (int i = 0; i < 5; ++i) svP[i] = sv[i];
        F13P = F13; F14P = F14; d13P = d13; d14P = d14;
        S13P = S13; S14P = S14; hjP = hj; z3P = z3; z4P = z4;
        z3 = z3n; z4 = z4n; F3p = F3n; F4p = F4n;
        tj = ptj; tj1 = ptj1; t0 = pt0;
    }

    // ---- epilogue: sweep2(block nblk-1) ----
    {
        float S23, S24;
        SWEEP2(svP, F13P, F14P, d13P, d14P, S13P, S14P, hjP, z3P, z4P, S23, S24);
        const int pbase = (nblk - 1) << 6;
        if (pbase + j < N)
            orow[pbase + j + 1] = make_float2(Y3 + S23, Y4 + S24);
    }
}

extern "C" void kernel_launch(void* const* d_in, const int* in_sizes, int n_in,
                              void* d_out, int out_size, void* d_ws, size_t ws_size,
                              hipStream_t stream) {
    const float* thr = (const float*)d_in[0];
    const float* DOD = (const float*)d_in[1];
    const float* Vav = (const float*)d_in[2];
    const float* C0  = (const float*)d_in[3];
    const float* R0  = (const float*)d_in[4];
    const float* W1  = (const float*)d_in[5];
    const float* b1  = (const float*)d_in[6];
    const float* W2  = (const float*)d_in[7];
    const float* b2  = (const float*)d_in[8];
    float* out = (float*)d_out;

    int B = in_sizes[1];             // DOD is (1,B)
    int N = in_sizes[0] / B - 1;     // throughput is (B, N+1)

    dim3 block(64);
    dim3 grid(B);                    // 1 row per 64-thread wave
    ode_wf64pipe<<<grid, block, 0, stream>>>(thr, DOD, Vav, C0, R0,
                                             W1, b1, W2, b2, out, B, N);
}

// Round 16
// 50.776 us; speedup vs baseline: 1.2383x; 1.2383x over previous
//
#include <hip/hip_runtime.h>

typedef float v2f __attribute__((ext_vector_type(2)));

// Canonical wave64 inclusive prefix-sum (AMD GCN scan sequence).
__device__ __forceinline__ float scan64(float d) {
    d += __int_as_float(__builtin_amdgcn_update_dpp(0, __float_as_int(d), 0x111, 0xF, 0xF, true));
    d += __int_as_float(__builtin_amdgcn_update_dpp(0, __float_as_int(d), 0x112, 0xF, 0xF, true));
    d += __int_as_float(__builtin_amdgcn_update_dpp(0, __float_as_int(d), 0x114, 0xF, 0xF, true));
    d += __int_as_float(__builtin_amdgcn_update_dpp(0, __float_as_int(d), 0x118, 0xF, 0xF, true));
    d += __int_as_float(__builtin_amdgcn_update_dpp(0, __float_as_int(d), 0x142, 0xA, 0xF, true));
    d += __int_as_float(__builtin_amdgcn_update_dpp(0, __float_as_int(d), 0x143, 0xC, 0xF, true));
    return d;
}

// wave-uniform broadcast of lane 63 (no LDS round-trip)
__device__ __forceinline__ float rdl63(float v) {
    return __int_as_float(__builtin_amdgcn_readlane(__float_as_int(v), 63));
}

// 128-step blocks, ONE wave, 2 steps per lane (lane j owns steps 2j, 2j+1).
// One scan-pair covers 128 steps; serial blocks halve to 16. Sweep2 is the
// round-14 linearized correction (zero transcendentals). 128-span NSWEEP=2
// numerics validated in rounds 11-13; linearization validated in round 14.
__global__ __launch_bounds__(64, 4) void ode_wf128x2(
    const float* __restrict__ thr,   // B x (N+1)
    const float* __restrict__ DOD,   // B
    const float* __restrict__ Vav,   // B
    const float* __restrict__ C0,    // B
    const float* __restrict__ R0,    // B
    const float* __restrict__ W1,    // 10 x 5
    const float* __restrict__ b1,    // 10
    const float* __restrict__ W2,    // 5 x 10
    const float* __restrict__ b2,    // 5
    float* __restrict__ out,         // B x (N+1) x 2
    int B, int N)
{
    const int j   = threadIdx.x & 63;
    const int row = blockIdx.x;         // 1 row per wave
    if (row >= B) return;

    // tanh(p) = 1 - 2/(1+e^{2p}); fold 2*log2(e) into layer-1, "+1" into
    // c3/c4, "-2" into wa/wb. Hidden units packed (h, h+5) -> v_pk_* fp32.
    const float k2  = 2.0f * 1.4426950408889634f;
    const float ln2 = 0.6931471805599453f;
    const float dod = DOD[row], vav = Vav[row];

    v2f bw[5], w0k[5], w3k[5], w4k[5], wa[5], wb[5];
    float c3 = b2[3], c4 = b2[4];
#pragma unroll
    for (int i = 0; i < 5; ++i) {
#pragma unroll
        for (int p = 0; p < 2; ++p) {
            int h = i + 5 * p;
            float a0 = W1[h * 5 + 0];
            float a1 = W1[h * 5 + 1];
            float a2 = W1[h * 5 + 2];
            float a3 = W1[h * 5 + 3];
            float a4 = W1[h * 5 + 4];
            bw[i][p]  = k2 * (b1[h] + a1 * dod + a2 * vav);
            w0k[i][p] = k2 * a0;
            w3k[i][p] = k2 * a3;
            w4k[i][p] = k2 * a4;
            float v3 = W2[30 + h];
            float v4 = W2[40 + h];
            c3 += v3; c4 += v4;
            wa[i][p] = -2.0f * v3;
            wb[i][p] = -2.0f * v4;
        }
    }

    float Y3 = C0[row], Y4 = R0[row];            // exact state entering block
    const float* trp = thr + (size_t)row * (size_t)(N + 1);
    float2* orow = (float2*)(out + (size_t)row * (size_t)(N + 1) * 2);
    if (j == 0) orow[0] = make_float2(Y3, Y4);

    // full MLP eval (keeps s for the Jacobian)
    auto MLP = [&](float z3_, float z4_, const v2f* bwt_, v2f* sv_,
                   float& F3_, float& F4_) {
        v2f Fa = {c3, 0.f}, Fb = {c4, 0.f};
#pragma unroll
        for (int i = 0; i < 5; ++i) {
            v2f x = w3k[i] * z3_ + (w4k[i] * z4_ + bwt_[i]);
            v2f e; e.x = __builtin_amdgcn_exp2f(x.x);
                   e.y = __builtin_amdgcn_exp2f(x.y);
            v2f A = e + 1.0f;
            v2f s; s.x = __builtin_amdgcn_rcpf(A.x);
                   s.y = __builtin_amdgcn_rcpf(A.y);
            sv_[i] = s;
            Fa += wa[i] * s;
            Fb += wb[i] * s;
        }
        F3_ = Fa.x + Fa.y; F4_ = Fb.x + Fb.y;
    };
    // linearized slope correction: F' = F - ln2 * sum(w{a,b} * s(1-s) * dx)
    auto JCOR = [&](const v2f* sv_, float dz3_, float dz4_,
                    float F3_, float F4_, float& F3o_, float& F4o_) {
        v2f a3 = {0.f, 0.f}, a4 = {0.f, 0.f};
#pragma unroll
        for (int i = 0; i < 5; ++i) {
            v2f dx = w3k[i] * dz3_ + w4k[i] * dz4_;
            v2f s  = sv_[i];
            v2f t  = s - s * s;
            v2f u  = dx * t;
            a3 += wa[i] * u;
            a4 += wb[i] * u;
        }
        F3o_ = fmaf(-ln2, a3.x + a3.y, F3_);
        F4o_ = fmaf(-ln2, a4.x + a4.y, F4_);
    };

    // t for block 0: lane j needs t[2j], t[2j+1], t[2j+2] + block base
    float t0 = trp[min(2 * j, N)];
    float t1 = trp[min(2 * j + 1, N)];
    float te = trp[min(2 * j + 2, N)];
    float tb = trp[0];

    // bootstrap slope F(Y, tb)
    float F3p, F4p;
    {
        v2f bwt[5], sv[5];
#pragma unroll
        for (int i = 0; i < 5; ++i) bwt[i] = w0k[i] * tb + bw[i];
        MLP(Y3, Y4, bwt, sv, F3p, F4p);
    }
    float dF3 = 0.f, dF4 = 0.f;

    const int nblk = (N + 127) >> 7;
    const int gInt = max(0, N / 128 - 1);        // g<gInt: next-block loads unclamped

    for (int g = 0; g < nblk; ++g) {
        const int base = g << 7;
        const int nb = base + 128;

        // prefetch next block's t (lands during the sweeps)
        float pt0, pt1, pte, ptb;
        if (g < gInt) {
            pt0 = trp[nb + 2 * j];
            pt1 = trp[nb + 2 * j + 1];
            pte = trp[nb + 2 * j + 2];
            ptb = trp[nb];
        } else {
            pt0 = trp[min(nb + 2 * j, N)];
            pt1 = trp[min(nb + 2 * j + 1, N)];
            pte = trp[min(nb + 2 * j + 2, N)];
            ptb = trp[min(nb, N)];
        }

        const float h0 = t1 - t0;                // 0 on clamped lanes
        const float h1 = te - t1;
        v2f bwt0[5], bwt1[5];
#pragma unroll
        for (int i = 0; i < 5; ++i) {
            bwt0[i] = w0k[i] * t0 + bw[i];
            bwt1[i] = w0k[i] * t1 + bw[i];
        }

        // 2nd-order predictor at both points
        const float dt0 = t0 - tb, dt1 = t1 - tb;
        float z30 = fmaf(dt0, fmaf(0.5f * dt0, dF3, F3p), Y3);
        float z40 = fmaf(dt0, fmaf(0.5f * dt0, dF4, F4p), Y4);
        float z31 = fmaf(dt1, fmaf(0.5f * dt1, dF3, F3p), Y3);
        float z41 = fmaf(dt1, fmaf(0.5f * dt1, dF4, F4p), Y4);

        // ---- sweep 1: two full MLP evals, one scan-pair over 128 steps ----
        v2f s0[5], s1[5];
        float F3a, F4a, F3b, F4b;
        MLP(z30, z40, bwt0, s0, F3a, F4a);
        MLP(z31, z41, bwt1, s1, F3b, F4b);
        float d3 = fmaf(h0, F3a, h1 * F3b);
        float d4 = fmaf(h0, F4a, h1 * F4b);
        float S3 = scan64(d3);
        float S4 = scan64(d4);
        // corrected states: point0 = exclusive prefix; point1 = +h0*F(point0)
        float c30 = Y3 + (S3 - d3);
        float c40 = Y4 + (S4 - d4);
        float c31 = fmaf(h0, F3a, c30);
        float c41 = fmaf(h0, F4a, c40);

        // ---- sweep 2: linearized (zero trans), one scan-pair ----
        float F3a2, F4a2, F3b2, F4b2;
        JCOR(s0, c30 - z30, c40 - z40, F3a, F4a, F3a2, F4a2);
        JCOR(s1, c31 - z31, c41 - z41, F3b, F4b, F3b2, F4b2);
        float d3p = fmaf(h0, F3a2, h1 * F3b2);
        float d4p = fmaf(h0, F4a2, h1 * F4b2);
        float S3p = scan64(d3p);
        float S4p = scan64(d4p);

        // outputs: after step 2j+1 = Y + inclusive; after step 2j = that - h1*F1
        float o31 = Y3 + S3p;
        float o41 = Y4 + S4p;
        float o30 = fmaf(-h1, F3b2, o31);
        float o40 = fmaf(-h1, F4b2, o41);
        const int p0 = base + 2 * j;
        if (p0 < N)     orow[p0 + 1] = make_float2(o30, o40);
        if (p0 + 1 < N) orow[p0 + 2] = make_float2(o31, o41);

        // carry via readlane
        float F3n = rdl63(F3b2);
        float F4n = rdl63(F4b2);
        Y3 += rdl63(S3p);
        Y4 += rdl63(S4p);
        float span = ptb - tb;
        float inv = (span > 0.f) ? __builtin_amdgcn_rcpf(span) : 0.f;
        dF3 = (F3n - F3p) * inv;
        dF4 = (F4n - F4p) * inv;
        F3p = F3n; F4p = F4n;

        t0 = pt0; t1 = pt1; te = pte; tb = ptb;
    }
}

extern "C" void kernel_launch(void* const* d_in, const int* in_sizes, int n_in,
                              void* d_out, int out_size, void* d_ws, size_t ws_size,
                              hipStream_t stream) {
    const float* thr = (const float*)d_in[0];
    const float* DOD = (const float*)d_in[1];
    const float* Vav = (const float*)d_in[2];
    const float* C0  = (const float*)d_in[3];
    const float* R0  = (const float*)d_in[4];
    const float* W1  = (const float*)d_in[5];
    const float* b1  = (const float*)d_in[6];
    const float* W2  = (const float*)d_in[7];
    const float* b2  = (const float*)d_in[8];
    float* out = (float*)d_out;

    int B = in_sizes[1];             // DOD is (1,B)
    int N = in_sizes[0] / B - 1;     // throughput is (B, N+1)

    dim3 block(64);
    dim3 grid(B);                    // 1 row per 64-thread wave
    ode_wf128x2<<<grid, block, 0, stream>>>(thr, DOD, Vav, C0, R0,
                                            W1, b1, W2, b2, out, B, N);
}

// Round 17
// 42.250 us; speedup vs baseline: 1.4882x; 1.2018x over previous
//
#include <hip/hip_runtime.h>

typedef float v2f __attribute__((ext_vector_type(2)));

// Canonical wave64 inclusive prefix-sum (AMD GCN scan sequence).
__device__ __forceinline__ float scan64(float d) {
    d += __int_as_float(__builtin_amdgcn_update_dpp(0, __float_as_int(d), 0x111, 0xF, 0xF, true));
    d += __int_as_float(__builtin_amdgcn_update_dpp(0, __float_as_int(d), 0x112, 0xF, 0xF, true));
    d += __int_as_float(__builtin_amdgcn_update_dpp(0, __float_as_int(d), 0x114, 0xF, 0xF, true));
    d += __int_as_float(__builtin_amdgcn_update_dpp(0, __float_as_int(d), 0x118, 0xF, 0xF, true));
    d += __int_as_float(__builtin_amdgcn_update_dpp(0, __float_as_int(d), 0x142, 0xA, 0xF, true));
    d += __int_as_float(__builtin_amdgcn_update_dpp(0, __float_as_int(d), 0x143, 0xC, 0xF, true));
    return d;
}

// wave-uniform broadcast of lane 63 (no LDS round-trip)
__device__ __forceinline__ float rdl63(float v) {
    return __int_as_float(__builtin_amdgcn_readlane(__float_as_int(v), 63));
}

// 128-step blocks, 2 steps/lane, ONE full MLP eval per lane per block:
// the slope at point 2j+1 comes from the Jacobian linearization (validated
// r14: bit-identical absmax), sweep-2's two corrections are fused into one
// J application by linearity, and output recovery reuses uncorrected F1
// (error h1*J*dc1 ~ 1e-5, non-propagating). Trans per block: 40 -> 20.
__global__ __launch_bounds__(64, 4) void ode_wf128x2b(
    const float* __restrict__ thr,   // B x (N+1)
    const float* __restrict__ DOD,   // B
    const float* __restrict__ Vav,   // B
    const float* __restrict__ C0,    // B
    const float* __restrict__ R0,    // B
    const float* __restrict__ W1,    // 10 x 5
    const float* __restrict__ b1,    // 10
    const float* __restrict__ W2,    // 5 x 10
    const float* __restrict__ b2,    // 5
    float* __restrict__ out,         // B x (N+1) x 2
    int B, int N)
{
    const int j   = threadIdx.x & 63;
    const int row = blockIdx.x;         // 1 row per wave
    if (row >= B) return;

    // tanh(p) = 1 - 2/(1+e^{2p}); fold 2*log2(e) into layer-1, "+1" into
    // c3/c4, "-2" into wa/wb. Hidden units packed (h, h+5) -> v_pk_* fp32.
    const float k2  = 2.0f * 1.4426950408889634f;
    const float ln2 = 0.6931471805599453f;
    const float dod = DOD[row], vav = Vav[row];

    v2f bw[5], w0k[5], w3k[5], w4k[5], wa[5], wb[5];
    float c3 = b2[3], c4 = b2[4];
#pragma unroll
    for (int i = 0; i < 5; ++i) {
#pragma unroll
        for (int p = 0; p < 2; ++p) {
            int h = i + 5 * p;
            float a0 = W1[h * 5 + 0];
            float a1 = W1[h * 5 + 1];
            float a2 = W1[h * 5 + 2];
            float a3 = W1[h * 5 + 3];
            float a4 = W1[h * 5 + 4];
            bw[i][p]  = k2 * (b1[h] + a1 * dod + a2 * vav);
            w0k[i][p] = k2 * a0;
            w3k[i][p] = k2 * a3;
            w4k[i][p] = k2 * a4;
            float v3 = W2[30 + h];
            float v4 = W2[40 + h];
            c3 += v3; c4 += v4;
            wa[i][p] = -2.0f * v3;
            wb[i][p] = -2.0f * v4;
        }
    }

    float Y3 = C0[row], Y4 = R0[row];            // exact state entering block
    const float* trp = thr + (size_t)row * (size_t)(N + 1);
    float2* orow = (float2*)(out + (size_t)row * (size_t)(N + 1) * 2);
    if (j == 0) orow[0] = make_float2(Y3, Y4);

    // t for block 0: lane j needs t[2j], t[2j+1], t[2j+2] + block base
    float t0 = trp[min(2 * j, N)];
    float t1 = trp[min(2 * j + 1, N)];
    float te = trp[min(2 * j + 2, N)];
    float tb = trp[0];

    // bootstrap slope F(Y, tb)
    float F3p, F4p;
    {
        v2f Fa = {c3, 0.f}, Fb = {c4, 0.f};
#pragma unroll
        for (int i = 0; i < 5; ++i) {
            v2f x = w3k[i] * Y3 + (w4k[i] * Y4 + (w0k[i] * tb + bw[i]));
            v2f e; e.x = __builtin_amdgcn_exp2f(x.x); e.y = __builtin_amdgcn_exp2f(x.y);
            v2f A = e + 1.0f;
            v2f s; s.x = __builtin_amdgcn_rcpf(A.x); s.y = __builtin_amdgcn_rcpf(A.y);
            Fa += wa[i] * s;
            Fb += wb[i] * s;
        }
        F3p = Fa.x + Fa.y; F4p = Fb.x + Fb.y;
    }
    float dF3 = 0.f, dF4 = 0.f;

    const int nblk = (N + 127) >> 7;
    const int gInt = max(0, N / 128 - 1);        // g<gInt: next-block loads unclamped

    for (int g = 0; g < nblk; ++g) {
        const int base = g << 7;
        const int nb = base + 128;

        // prefetch next block's t (lands during the sweeps)
        float pt0, pt1, pte, ptb;
        if (g < gInt) {
            pt0 = trp[nb + 2 * j];
            pt1 = trp[nb + 2 * j + 1];
            pte = trp[nb + 2 * j + 2];
            ptb = trp[nb];
        } else {
            pt0 = trp[min(nb + 2 * j, N)];
            pt1 = trp[min(nb + 2 * j + 1, N)];
            pte = trp[min(nb + 2 * j + 2, N)];
            ptb = trp[min(nb, N)];
        }

        const float h0 = t1 - t0;                // 0 on clamped lanes
        const float h1 = te - t1;

        // 2nd-order predictor at both points
        const float dt0 = t0 - tb, dt1 = t1 - tb;
        float z30 = fmaf(dt0, fmaf(0.5f * dt0, dF3, F3p), Y3);
        float z40 = fmaf(dt0, fmaf(0.5f * dt0, dF4, F4p), Y4);
        float z31 = fmaf(dt1, fmaf(0.5f * dt1, dF3, F3p), Y3);
        float z41 = fmaf(dt1, fmaf(0.5f * dt1, dF4, F4p), Y4);

        // ---- ONE full MLP eval at (z30, z40, t0); keep s -> Jacobian wt ----
        v2f tq[5];                               // s, then s*(1-s) in place
        float F30, F40;
        {
            v2f Fa = {c3, 0.f}, Fb = {c4, 0.f};
#pragma unroll
            for (int i = 0; i < 5; ++i) {
                v2f x = w3k[i] * z30 + (w4k[i] * z40 + (w0k[i] * t0 + bw[i]));
                v2f e; e.x = __builtin_amdgcn_exp2f(x.x);
                       e.y = __builtin_amdgcn_exp2f(x.y);
                v2f A = e + 1.0f;
                v2f s; s.x = __builtin_amdgcn_rcpf(A.x);
                       s.y = __builtin_amdgcn_rcpf(A.y);
                tq[i] = s;
                Fa += wa[i] * s;
                Fb += wb[i] * s;
            }
            F30 = Fa.x + Fa.y; F40 = Fb.x + Fb.y;
        }
#pragma unroll
        for (int i = 0; i < 5; ++i) tq[i] = tq[i] - tq[i] * tq[i];  // s(1-s)

        // ---- slope at point 1 via J (includes the dt term w0k*h0) ----
        const float dz3 = z31 - z30, dz4 = z41 - z40;
        float F31, F41;
        {
            v2f a3 = {0.f, 0.f}, a4 = {0.f, 0.f};
#pragma unroll
            for (int i = 0; i < 5; ++i) {
                v2f dx = w0k[i] * h0 + (w3k[i] * dz3 + w4k[i] * dz4);
                v2f u  = dx * tq[i];
                a3 += wa[i] * u;
                a4 += wb[i] * u;
            }
            F31 = fmaf(-ln2, a3.x + a3.y, F30);
            F41 = fmaf(-ln2, a4.x + a4.y, F40);
        }

        // ---- sweep 1 scan over 128 steps ----
        float d3 = fmaf(h0, F30, h1 * F31);
        float d4 = fmaf(h0, F40, h1 * F41);
        float S3 = scan64(d3);
        float S4 = scan64(d4);
        float c30 = Y3 + (S3 - d3), c40 = Y4 + (S4 - d4);
        float c31 = fmaf(h0, F30, c30), c41 = fmaf(h0, F40, c40);

        // ---- sweep 2 fused: d' = d + J·(h0*dc0 + h1*dc1) (linearity) ----
        float dm3 = fmaf(h0, c30 - z30, h1 * (c31 - z31));
        float dm4 = fmaf(h0, c40 - z40, h1 * (c41 - z41));
        float d3p, d4p;
        {
            v2f a3 = {0.f, 0.f}, a4 = {0.f, 0.f};
#pragma unroll
            for (int i = 0; i < 5; ++i) {
                v2f dx = w3k[i] * dm3 + w4k[i] * dm4;
                v2f u  = dx * tq[i];
                a3 += wa[i] * u;
                a4 += wb[i] * u;
            }
            d3p = fmaf(-ln2, a3.x + a3.y, d3);
            d4p = fmaf(-ln2, a4.x + a4.y, d4);
        }
        float S3p = scan64(d3p);
        float S4p = scan64(d4p);

        // outputs: after step 2j+1 = Y + inclusive; point 0 recovered via F31
        float o31 = Y3 + S3p;
        float o41 = Y4 + S4p;
        float o30 = fmaf(-h1, F31, o31);
        float o40 = fmaf(-h1, F41, o41);
        const int p0 = base + 2 * j;
        if (p0 < N)     orow[p0 + 1] = make_float2(o30, o40);
        if (p0 + 1 < N) orow[p0 + 2] = make_float2(o31, o41);

        // carry via readlane
        float F3n = rdl63(F31);
        float F4n = rdl63(F41);
        Y3 += rdl63(S3p);
        Y4 += rdl63(S4p);
        float span = ptb - tb;
        float inv = (span > 0.f) ? __builtin_amdgcn_rcpf(span) : 0.f;
        dF3 = (F3n - F3p) * inv;
        dF4 = (F4n - F4p) * inv;
        F3p = F3n; F4p = F4n;

        t0 = pt0; t1 = pt1; te = pte; tb = ptb;
    }
}

extern "C" void kernel_launch(void* const* d_in, const int* in_sizes, int n_in,
                              void* d_out, int out_size, void* d_ws, size_t ws_size,
                              hipStream_t stream) {
    const float* thr = (const float*)d_in[0];
    const float* DOD = (const float*)d_in[1];
    const float* Vav = (const float*)d_in[2];
    const float* C0  = (const float*)d_in[3];
    const float* R0  = (const float*)d_in[4];
    const float* W1  = (const float*)d_in[5];
    const float* b1  = (const float*)d_in[6];
    const float* W2  = (const float*)d_in[7];
    const float* b2  = (const float*)d_in[8];
    float* out = (float*)d_out;

    int B = in_sizes[1];             // DOD is (1,B)
    int N = in_sizes[0] / B - 1;     // throughput is (B, N+1)

    dim3 block(64);
    dim3 grid(B);                    // 1 row per 64-thread wave
    ode_wf128x2b<<<grid, block, 0, stream>>>(thr, DOD, Vav, C0, R0,
                                             W1, b1, W2, b2, out, B, N);
}

// Round 18
// 33.847 us; speedup vs baseline: 1.8576x; 1.2483x over previous
//
#include <hip/hip_runtime.h>

typedef float v2f __attribute__((ext_vector_type(2)));

// Canonical wave64 inclusive prefix-sum (AMD GCN scan sequence).
__device__ __forceinline__ float scan64(float d) {
    d += __int_as_float(__builtin_amdgcn_update_dpp(0, __float_as_int(d), 0x111, 0xF, 0xF, true));
    d += __int_as_float(__builtin_amdgcn_update_dpp(0, __float_as_int(d), 0x112, 0xF, 0xF, true));
    d += __int_as_float(__builtin_amdgcn_update_dpp(0, __float_as_int(d), 0x114, 0xF, 0xF, true));
    d += __int_as_float(__builtin_amdgcn_update_dpp(0, __float_as_int(d), 0x118, 0xF, 0xF, true));
    d += __int_as_float(__builtin_amdgcn_update_dpp(0, __float_as_int(d), 0x142, 0xA, 0xF, true));
    d += __int_as_float(__builtin_amdgcn_update_dpp(0, __float_as_int(d), 0x143, 0xC, 0xF, true));
    return d;
}

// wave-uniform broadcast of lane 63 (no LDS round-trip)
__device__ __forceinline__ float rdl63(float v) {
    return __int_as_float(__builtin_amdgcn_readlane(__float_as_int(v), 63));
}

// 256-step blocks, 4 steps/lane. ONE full MLP per lane per block; the
// Jacobian is collapsed into 6 per-lane scalars K (pre-scaled by ln2), so
// the 3 extra point-slopes and the fused sweep-2 are a handful of scalar
// FMAs each. 8 serial blocks. Validated lineage: 128-span NSWEEP=2 (r11-13),
// J-linearization (r14/r17) - all bit-identical absmax 0.03125.
__global__ __launch_bounds__(64, 4) void ode_wf256x4(
    const float* __restrict__ thr,   // B x (N+1)
    const float* __restrict__ DOD,   // B
    const float* __restrict__ Vav,   // B
    const float* __restrict__ C0,    // B
    const float* __restrict__ R0,    // B
    const float* __restrict__ W1,    // 10 x 5
    const float* __restrict__ b1,    // 10
    const float* __restrict__ W2,    // 5 x 10
    const float* __restrict__ b2,    // 5
    float* __restrict__ out,         // B x (N+1) x 2
    int B, int N)
{
    const int j   = threadIdx.x & 63;
    const int row = blockIdx.x;         // 1 row per wave
    if (row >= B) return;

    // tanh(p) = 1 - 2/(1+e^{2p}); fold 2*log2(e) into layer-1, "+1" into
    // c3/c4, "-2" into wa/wb. Hidden units packed (h, h+5) -> v_pk_* fp32.
    const float k2  = 2.0f * 1.4426950408889634f;
    const float ln2 = 0.6931471805599453f;
    const float dod = DOD[row], vav = Vav[row];

    v2f bw[5], w0k[5], w3k[5], w4k[5], wa[5], wb[5];
    float c3 = b2[3], c4 = b2[4];
#pragma unroll
    for (int i = 0; i < 5; ++i) {
#pragma unroll
        for (int p = 0; p < 2; ++p) {
            int h = i + 5 * p;
            float a0 = W1[h * 5 + 0];
            float a1 = W1[h * 5 + 1];
            float a2 = W1[h * 5 + 2];
            float a3 = W1[h * 5 + 3];
            float a4 = W1[h * 5 + 4];
            bw[i][p]  = k2 * (b1[h] + a1 * dod + a2 * vav);
            w0k[i][p] = k2 * a0;
            w3k[i][p] = k2 * a3;
            w4k[i][p] = k2 * a4;
            float v3 = W2[30 + h];
            float v4 = W2[40 + h];
            c3 += v3; c4 += v4;
            wa[i][p] = -2.0f * v3;
            wb[i][p] = -2.0f * v4;
        }
    }

    float Y3 = C0[row], Y4 = R0[row];            // exact state entering block
    const float* trp = thr + (size_t)row * (size_t)(N + 1);
    float2* orow = (float2*)(out + (size_t)row * (size_t)(N + 1) * 2);
    if (j == 0) orow[0] = make_float2(Y3, Y4);

    // t for block 0: lane j needs t[4j .. 4j+4] + block base
    float t[5];
#pragma unroll
    for (int k = 0; k < 5; ++k) t[k] = trp[min(4 * j + k, N)];
    float tb = trp[0];

    // bootstrap slope F(Y, tb)
    float F3p, F4p;
    {
        v2f Fa = {c3, 0.f}, Fb = {c4, 0.f};
#pragma unroll
        for (int i = 0; i < 5; ++i) {
            v2f x = w3k[i] * Y3 + (w4k[i] * Y4 + (w0k[i] * tb + bw[i]));
            v2f e; e.x = __builtin_amdgcn_exp2f(x.x); e.y = __builtin_amdgcn_exp2f(x.y);
            v2f A = e + 1.0f;
            v2f s; s.x = __builtin_amdgcn_rcpf(A.x); s.y = __builtin_amdgcn_rcpf(A.y);
            Fa += wa[i] * s;
            Fb += wb[i] * s;
        }
        F3p = Fa.x + Fa.y; F4p = Fb.x + Fb.y;
    }
    float dF3 = 0.f, dF4 = 0.f;

    const int nblk = (N + 255) >> 8;
    const int gInt = max(0, N / 256 - 1);        // g<gInt: next-block loads unclamped

    for (int g = 0; g < nblk; ++g) {
        const int base = g << 8;
        const int nb = base + 256;

        // prefetch next block's t (lands during the sweeps)
        float pt[5], ptb;
        if (g < gInt) {
#pragma unroll
            for (int k = 0; k < 5; ++k) pt[k] = trp[nb + 4 * j + k];
            ptb = trp[nb];
        } else {
#pragma unroll
            for (int k = 0; k < 5; ++k) pt[k] = trp[min(nb + 4 * j + k, N)];
            ptb = trp[min(nb, N)];
        }

        const float h0 = t[1] - t[0];            // 0 on clamped lanes
        const float h1 = t[2] - t[1];
        const float h2 = t[3] - t[2];
        const float h3 = t[4] - t[3];

        // 2nd-order predictor at the 4 points
        float z3[4], z4[4];
#pragma unroll
        for (int k = 0; k < 4; ++k) {
            float dt = t[k] - tb;
            z3[k] = fmaf(dt, fmaf(0.5f * dt, dF3, F3p), Y3);
            z4[k] = fmaf(dt, fmaf(0.5f * dt, dF4, F4p), Y4);
        }

        // ---- ONE full MLP eval at (z[0], t0); keep s -> Jacobian weights ----
        v2f tq[5];
        float F30, F40;
        {
            v2f Fa = {c3, 0.f}, Fb = {c4, 0.f};
#pragma unroll
            for (int i = 0; i < 5; ++i) {
                v2f x = w3k[i] * z3[0] + (w4k[i] * z4[0] + (w0k[i] * t[0] + bw[i]));
                v2f e; e.x = __builtin_amdgcn_exp2f(x.x);
                       e.y = __builtin_amdgcn_exp2f(x.y);
                v2f A = e + 1.0f;
                v2f s; s.x = __builtin_amdgcn_rcpf(A.x);
                       s.y = __builtin_amdgcn_rcpf(A.y);
                tq[i] = s;
                Fa += wa[i] * s;
                Fb += wb[i] * s;
            }
            F30 = Fa.x + Fa.y; F40 = Fb.x + Fb.y;
        }
#pragma unroll
        for (int i = 0; i < 5; ++i) tq[i] = tq[i] - tq[i] * tq[i];  // s(1-s)

        // ---- Jacobian collapsed to 6 per-lane scalars (pre-scaled ln2) ----
        float K3a, K4a, Kta, K3b, K4b, Ktb;
        {
            v2f a3 = {0.f,0.f}, a4 = {0.f,0.f}, at = {0.f,0.f};
            v2f b3 = {0.f,0.f}, b4 = {0.f,0.f}, bt = {0.f,0.f};
#pragma unroll
            for (int i = 0; i < 5; ++i) {
                v2f ma = wa[i] * tq[i];
                v2f mb = wb[i] * tq[i];
                a3 += ma * w3k[i]; a4 += ma * w4k[i]; at += ma * w0k[i];
                b3 += mb * w3k[i]; b4 += mb * w4k[i]; bt += mb * w0k[i];
            }
            K3a = ln2 * (a3.x + a3.y); K4a = ln2 * (a4.x + a4.y);
            Kta = ln2 * (at.x + at.y);
            K3b = ln2 * (b3.x + b3.y); K4b = ln2 * (b4.x + b4.y);
            Ktb = ln2 * (bt.x + bt.y);
        }

        // ---- slopes at points 1..3 via J (scalar form) ----
        float F3v[4], F4v[4];
        F3v[0] = F30; F4v[0] = F40;
#pragma unroll
        for (int k = 1; k < 4; ++k) {
            float D3 = z3[k] - z3[0];
            float D4 = z4[k] - z4[0];
            float Dt = t[k] - t[0];
            F3v[k] = F30 - fmaf(K3a, D3, fmaf(K4a, D4, Kta * Dt));
            F4v[k] = F40 - fmaf(K3b, D3, fmaf(K4b, D4, Ktb * Dt));
        }

        // ---- sweep 1: combined increment, one scan-pair over 256 steps ----
        float d3 = fmaf(h0, F3v[0], fmaf(h1, F3v[1], fmaf(h2, F3v[2], h3 * F3v[3])));
        float d4 = fmaf(h0, F4v[0], fmaf(h1, F4v[1], fmaf(h2, F4v[2], h3 * F4v[3])));
        float S3 = scan64(d3);
        float S4 = scan64(d4);

        // corrected states (local Euler walk) -> h-weighted correction dm
        float dm3, dm4;
        {
            float cc3 = Y3 + (S3 - d3), cc4 = Y4 + (S4 - d4);
            dm3 = h0 * (cc3 - z3[0]);  dm4 = h0 * (cc4 - z4[0]);
            cc3 = fmaf(h0, F3v[0], cc3); cc4 = fmaf(h0, F4v[0], cc4);
            dm3 = fmaf(h1, cc3 - z3[1], dm3); dm4 = fmaf(h1, cc4 - z4[1], dm4);
            cc3 = fmaf(h1, F3v[1], cc3); cc4 = fmaf(h1, F4v[1], cc4);
            dm3 = fmaf(h2, cc3 - z3[2], dm3); dm4 = fmaf(h2, cc4 - z4[2], dm4);
            cc3 = fmaf(h2, F3v[2], cc3); cc4 = fmaf(h2, F4v[2], cc4);
            dm3 = fmaf(h3, cc3 - z3[3], dm3); dm4 = fmaf(h3, cc4 - z4[3], dm4);
        }

        // ---- sweep 2 fused through J (scalar), second scan-pair ----
        float d3p = d3 - fmaf(K3a, dm3, K4a * dm4);
        float d4p = d4 - fmaf(K3b, dm3, K4b * dm4);
        float S3p = scan64(d3p);
        float S4p = scan64(d4p);

        // ---- outputs: back-recovery from the step-(4j+3) state ----
        float o3 = Y3 + S3p, o4 = Y4 + S4p;
        const int p0 = base + 4 * j;
        if (p0 + 3 < N) orow[p0 + 4] = make_float2(o3, o4);
        float q3 = fmaf(-h3, F3v[3], o3), q4 = fmaf(-h3, F4v[3], o4);
        if (p0 + 2 < N) orow[p0 + 3] = make_float2(q3, q4);
        q3 = fmaf(-h2, F3v[2], q3); q4 = fmaf(-h2, F4v[2], q4);
        if (p0 + 1 < N) orow[p0 + 2] = make_float2(q3, q4);
        q3 = fmaf(-h1, F3v[1], q3); q4 = fmaf(-h1, F4v[1], q4);
        if (p0 < N)     orow[p0 + 1] = make_float2(q3, q4);

        // ---- carry via readlane ----
        float F3n = rdl63(F3v[3]);
        float F4n = rdl63(F4v[3]);
        Y3 += rdl63(S3p);
        Y4 += rdl63(S4p);
        float span = ptb - tb;
        float inv = (span > 0.f) ? __builtin_amdgcn_rcpf(span) : 0.f;
        dF3 = (F3n - F3p) * inv;
        dF4 = (F4n - F4p) * inv;
        F3p = F3n; F4p = F4n;

#pragma unroll
        for (int k = 0; k < 5; ++k) t[k] = pt[k];
        tb = ptb;
    }
}

extern "C" void kernel_launch(void* const* d_in, const int* in_sizes, int n_in,
                              void* d_out, int out_size, void* d_ws, size_t ws_size,
                              hipStream_t stream) {
    const float* thr = (const float*)d_in[0];
    const float* DOD = (const float*)d_in[1];
    const float* Vav = (const float*)d_in[2];
    const float* C0  = (const float*)d_in[3];
    const float* R0  = (const float*)d_in[4];
    const float* W1  = (const float*)d_in[5];
    const float* b1  = (const float*)d_in[6];
    const float* W2  = (const float*)d_in[7];
    const float* b2  = (const float*)d_in[8];
    float* out = (float*)d_out;

    int B = in_sizes[1];             // DOD is (1,B)
    int N = in_sizes[0] / B - 1;     // throughput is (B, N+1)

    dim3 block(64);
    dim3 grid(B);                    // 1 row per 64-thread wave
    ode_wf256x4<<<grid, block, 0, stream>>>(thr, DOD, Vav, C0, R0,
                                            W1, b1, W2, b2, out, B, N);
}